// Round 1
// baseline (271.039 us; speedup 1.0000x reference)
//
#include <hip/hip_runtime.h>
#include <math.h>

#pragma clang fp contract(off)

#define N_ANCH 17064
#define BATCH  16
#define NGT    32
#define BG_CLS 81
#define EPSF   1e-6f

// ---------- geometry ----------
struct Geo { int lvl; int j; int HW; float px; float py; float rf; };

__device__ __forceinline__ Geo geom(int n) {
  Geo g;
  if (n < 12800)      { g.lvl=0; g.j=n;       g.HW=12800; g.px=(float)((g.j & 127)*8 + 4);   g.py=(float)((g.j >> 7)*8 + 4);   g.rf=45.5f; }
  else if (n < 16000) { g.lvl=1; g.j=n-12800; g.HW=3200;  g.px=(float)((g.j & 63)*16 + 8);   g.py=(float)((g.j >> 6)*16 + 8);  g.rf=133.5f; }
  else if (n < 16800) { g.lvl=2; g.j=n-16000; g.HW=800;   g.px=(float)((g.j & 31)*32 + 16);  g.py=(float)((g.j >> 5)*32 + 16); g.rf=213.5f; }
  else if (n < 17008) { g.lvl=3; g.j=n-16800; g.HW=208;   g.px=(float)((g.j & 15)*64 + 32);  g.py=(float)((g.j >> 4)*64 + 32); g.rf=277.5f; }
  else                { g.lvl=4; g.j=n-17008; g.HW=56;    g.px=(float)((g.j & 7)*128 + 64);  g.py=(float)((g.j >> 3)*128 + 64);g.rf=405.5f; }
  return g;
}

__device__ __forceinline__ void rf1_box(float px, float py, float rf,
                                        float& a0, float& a1, float& a2, float& a3) {
  float rfh = rf * 0.5f;            // rf/2 exact
  a0 = px - rfh; a1 = py - rfh; a2 = px + rfh; a3 = py + rfh;
}

__device__ __forceinline__ void rf2_box(float a0, float a1, float a2, float a3,
                                        float& b0, float& b1, float& b2, float& b3) {
  float whx = (a2 - a0) * 0.9f, why = (a3 - a1) * 0.9f;
  float cx  = (a0 + a2) * 0.5f, cy  = (a1 + a3) * 0.5f;   // /2 exact
  b0 = cx - whx * 0.5f; b1 = cy - why * 0.5f;
  b2 = cx + whx * 0.5f; b3 = cy + why * 0.5f;
}

// KL overlap, replicating JAX expression order exactly.
__device__ __forceinline__ float kl_ov(float g0, float g1, float g2, float g3,
                                       float a0, float a1, float a2, float a3) {
  float c1x = (g0 + g2) * 0.5f;  // /2 exact
  float c1y = (g1 + g3) * 0.5f;
  float c2x = (a0 + a2) * 0.5f;
  float c2y = (a1 + a3) * 0.5f;
  float w1 = g2 - g0 + EPSF, h1 = g3 - g1 + EPSF;
  float w2 = a2 - a0 + EPSF, h2 = a3 - a1 + EPSF;
  float dx = c1x - c2x, dy = c1y - c2y;
  float w1s = w1 * w1, h1s = h1 * h1, w2s = w2 * w2, h2s = h2 * h2;
  float dx2 = dx * dx, dy2 = dy * dy;
  float t = w2s / w1s;
  t += h2s / h1s;
  t += (4.0f * dx2) / w1s;
  t += (4.0f * dy2) / h1s;
  t += logf(w1s / w2s);
  t += logf(h1s / h2s);
  t -= 2.0f;
  float kl = t * 0.5f;             // /2 exact
  return 1.0f / (1.0f + kl);
}

// ---------- top-k helpers (JAX tie rule: value desc, index asc) ----------
__device__ __forceinline__ bool better(float av, int ai, float bv, int bi) {
  return (av > bv) || (av == bv && ai < bi);
}

__device__ __forceinline__ void insert3(float* v, int* i, float nv, int ni) {
  if (better(nv, ni, v[0], i[0])) { v[2]=v[1]; i[2]=i[1]; v[1]=v[0]; i[1]=i[0]; v[0]=nv; i[0]=ni; }
  else if (better(nv, ni, v[1], i[1])) { v[2]=v[1]; i[2]=i[1]; v[1]=nv; i[1]=ni; }
  else if (better(nv, ni, v[2], i[2])) { v[2]=nv; i[2]=ni; }
}

// ---------- block reduce ----------
__device__ __forceinline__ void block_sum_atomic(float v, double* target, float* sh) {
  int t = threadIdx.x;
  sh[t] = v;
  __syncthreads();
  #pragma unroll
  for (int off = 128; off > 0; off >>= 1) {
    if (t < off) sh[t] += sh[t + off];
    __syncthreads();
  }
  if (t == 0) atomicAdd(target, (double)sh[0]);
  __syncthreads();
}

// ---------- Phase A: per-anchor max overlap -> assigned0 in {0,-1} ----------
__global__ __launch_bounds__(256) void phaseA(const float4* __restrict__ gtb,
                                              int* __restrict__ a0out) {
  __shared__ float4 sg[NGT];
  int b = blockIdx.y;
  if (threadIdx.x < NGT) sg[threadIdx.x] = gtb[b * NGT + threadIdx.x];
  __syncthreads();
  int n = blockIdx.x * 256 + threadIdx.x;
  if (n >= N_ANCH) return;
  Geo G = geom(n);
  float A0, A1, A2, A3;
  rf1_box(G.px, G.py, G.rf, A0, A1, A2, A3);
  float mx = -INFINITY;
  for (int g = 0; g < NGT; ++g) {
    float4 gb = sg[g];
    float o = kl_ov(gb.x, gb.y, gb.z, gb.w, A0, A1, A2, A3);
    mx = fmaxf(mx, o);
  }
  a0out[b * N_ANCH + n] = (mx >= 0.0f && mx < 0.8f) ? 0 : -1;
}

// ---------- Phase B: per-(b,g) top3 by ov1 and top1 by ov2 ----------
__global__ __launch_bounds__(256) void phaseB(const float4* __restrict__ gtb,
                                              int* __restrict__ sel) {
  int blk = blockIdx.x;
  int b = blk >> 5, g = blk & 31;
  float4 GB = gtb[b * NGT + g];
  int t = threadIdx.x;
  float v1[3] = {-INFINITY, -INFINITY, -INFINITY};
  int   i1[3] = {0x7fffffff, 0x7fffffff, 0x7fffffff};
  float v2 = -INFINITY; int i2 = 0x7fffffff;

  for (int n = t; n < N_ANCH; n += 256) {
    Geo G = geom(n);
    float a0, a1, a2, a3;
    rf1_box(G.px, G.py, G.rf, a0, a1, a2, a3);
    float o1 = kl_ov(GB.x, GB.y, GB.z, GB.w, a0, a1, a2, a3);
    if (better(o1, n, v1[2], i1[2])) insert3(v1, i1, o1, n);
    float b0, b1, b2, b3;
    rf2_box(a0, a1, a2, a3, b0, b1, b2, b3);
    float o2 = kl_ov(GB.x, GB.y, GB.z, GB.w, b0, b1, b2, b3);
    if (better(o2, n, v2, i2)) { v2 = o2; i2 = n; }
  }

  __shared__ float sv[256 * 3];
  __shared__ int   si[256 * 3];
  __shared__ float tv[256];
  __shared__ int   ti[256];
  sv[t*3+0] = v1[0]; sv[t*3+1] = v1[1]; sv[t*3+2] = v1[2];
  si[t*3+0] = i1[0]; si[t*3+1] = i1[1]; si[t*3+2] = i1[2];
  tv[t] = v2; ti[t] = i2;
  __syncthreads();
  for (int off = 128; off > 0; off >>= 1) {
    if (t < off) {
      #pragma unroll
      for (int k = 0; k < 3; ++k) {
        float nv = sv[(t + off) * 3 + k];
        int   ni = si[(t + off) * 3 + k];
        insert3(&sv[t * 3], &si[t * 3], nv, ni);
      }
      if (better(tv[t + off], ti[t + off], tv[t], ti[t])) { tv[t] = tv[t + off]; ti[t] = ti[t + off]; }
    }
    __syncthreads();
  }
  if (t == 0) {
    int base = b * N_ANCH;
    atomicMax(&sel[base + si[0]], 32 + g);   // tier1 (ov1 top3)
    atomicMax(&sel[base + si[1]], 32 + g);
    atomicMax(&sel[base + si[2]], 32 + g);
    atomicMax(&sel[base + ti[0]], 64 + g);   // tier2 (ov2 top1) always wins over tier1
  }
}

// ---------- Phase C: decode assignment -> labels + box targets ----------
__global__ __launch_bounds__(256) void phaseC(const float4* __restrict__ gtb,
                                              const int* __restrict__ glab,
                                              const int* __restrict__ sel,
                                              const int* __restrict__ a0in,
                                              int* __restrict__ labels,
                                              float4* __restrict__ btv) {
  int idx = blockIdx.x * 256 + threadIdx.x;
  if (idx >= BATCH * N_ANCH) return;
  int b = idx / N_ANCH;
  int n = idx - b * N_ANCH;
  int s = sel[idx];
  int assigned = (s >= 32) ? ((s & 31) + 1) : a0in[idx];
  int mi = (assigned >= 1) ? (assigned - 1) : 0;
  float4 gb = gtb[b * NGT + mi];
  Geo G = geom(n);
  btv[idx] = make_float4(G.px - gb.x, G.py - gb.y, gb.z - G.px, gb.w - G.py);
  labels[idx] = (assigned >= 1) ? glab[b * NGT + mi] : BG_CLS;
}

// ---------- Phase D1: focal classification loss ----------
__device__ __forceinline__ float cls_term(float x, bool tgt) {
  float p  = 1.0f / (1.0f + expf(-x));
  float pt = tgt ? (1.0f - p) : p;
  float fw = (tgt ? 0.25f : 0.75f) * (pt * pt);
  float bce = fmaxf(x, 0.0f) - (tgt ? x : 0.0f) + log1pf(expf(-fabsf(x)));
  return bce * fw;
}

template <int HW, int OFFSET>
__device__ __forceinline__ float cls_level(const float* __restrict__ cp,
                                           const int* __restrict__ labels) {
  constexpr int HW4 = HW / 4;
  const int total = BATCH * 81 * HW4;
  int gid = blockIdx.x * blockDim.x + threadIdx.x;
  int gsz = gridDim.x * blockDim.x;
  const float4* p4 = (const float4*)cp;
  float local = 0.0f;
  for (int idx = gid; idx < total; idx += gsz) {
    int j4 = idx % HW4;
    int r  = idx / HW4;
    int c  = r % 81;
    int b  = r / 81;
    float4 f = p4[idx];
    int4 l4 = *(const int4*)(labels + b * N_ANCH + OFFSET + (j4 << 2));
    local += cls_term(f.x, c == l4.x);
    local += cls_term(f.y, c == l4.y);
    local += cls_term(f.z, c == l4.z);
    local += cls_term(f.w, c == l4.w);
  }
  return local;
}

__global__ __launch_bounds__(256) void clsK(const float* __restrict__ c0, const float* __restrict__ c1,
                                            const float* __restrict__ c2, const float* __restrict__ c3,
                                            const float* __restrict__ c4,
                                            const int* __restrict__ labels, double* __restrict__ acc) {
  float local = 0.0f;
  local += cls_level<12800, 0>(c0, labels);
  local += cls_level<3200, 12800>(c1, labels);
  local += cls_level<800, 16000>(c2, labels);
  local += cls_level<208, 16800>(c3, labels);
  local += cls_level<56, 17008>(c4, labels);
  __shared__ float sh[256];
  block_sum_atomic(local, acc + 0, sh);
}

// ---------- Phase D2: DIoU + centerness ----------
__global__ __launch_bounds__(256) void boxK(
    const float* __restrict__ bb0, const float* __restrict__ bb1, const float* __restrict__ bb2,
    const float* __restrict__ bb3, const float* __restrict__ bb4,
    const float* __restrict__ ct0, const float* __restrict__ ct1, const float* __restrict__ ct2,
    const float* __restrict__ ct3, const float* __restrict__ ct4,
    const int* __restrict__ labels, const float4* __restrict__ btv, double* __restrict__ acc) {
  int idx = blockIdx.x * 256 + threadIdx.x;
  float s_pos = 0.f, s_ctr = 0.f, s_diou = 0.f, s_cbce = 0.f;
  if (idx < BATCH * N_ANCH) {
    int b = idx / N_ANCH;
    int n = idx - b * N_ANCH;
    Geo G = geom(n);
    const float* bb; const float* ct;
    if (G.lvl == 0)      { bb = bb0; ct = ct0; }
    else if (G.lvl == 1) { bb = bb1; ct = ct1; }
    else if (G.lvl == 2) { bb = bb2; ct = ct2; }
    else if (G.lvl == 3) { bb = bb3; ct = ct3; }
    else                 { bb = bb4; ct = ct4; }
    const float* bp = bb + b * 4 * G.HW + G.j;
    float f0 = bp[0];
    float f1 = bp[G.HW];
    float f2 = bp[2 * G.HW];
    float f3 = bp[3 * G.HW];
    float fo = ct[b * G.HW + G.j];
    int lab = labels[idx];
    bool pos = lab < BG_CLS;
    float posf = pos ? 1.0f : 0.0f;
    float4 t = pos ? btv[idx] : make_float4(1.f, 1.f, 1.f, 1.f);

    float lr_min = fminf(t.x, t.z), lr_max = fmaxf(t.x, t.z);
    float tb_min = fminf(t.y, t.w), tb_max = fmaxf(t.y, t.w);
    float prod = (lr_min / lr_max) * (tb_min / tb_max);
    float ctrt = sqrtf(fmaxf(prod, 0.0f)) * posf;

    float pb0 = G.px - f0, pb1 = G.py - f1, pb2 = G.px + f2, pb3 = G.py + f3;
    float tb0 = G.px - t.x, tb1 = G.py - t.y, tb2 = G.px + t.z, tb3 = G.py + t.w;

    float ltx = fmaxf(pb0, tb0), lty = fmaxf(pb1, tb1);
    float rbx = fminf(pb2, tb2), rby = fminf(pb3, tb3);
    float whx = fmaxf(rbx - ltx, 0.0f), why = fmaxf(rby - lty, 0.0f);
    float ovl = whx * why;
    float ap = (pb2 - pb0) * (pb3 - pb1);
    float ag = (tb2 - tb0) * (tb3 - tb1);
    float ious = ovl / (ap + ag - ovl + EPSF);
    float eltx = fminf(pb0, tb0), elty = fminf(pb1, tb1);
    float erbx = fmaxf(pb2, tb2), erby = fmaxf(pb3, tb3);
    float ewx = fmaxf(erbx - eltx, 0.0f), ewy = fmaxf(erby - elty, 0.0f);
    float c2v = ewx * ewx + ewy * ewy + EPSF;
    float sx = pb0 + pb2 - tb0 - tb2;
    float sy = pb1 + pb3 - tb1 - tb3;
    float rho2 = (sx * sx + sy * sy) * 0.25f;   // /4 exact
    float dl = 1.0f - (ious - rho2 / c2v);

    s_pos = posf;
    s_ctr = ctrt;
    s_diou = dl * ctrt;
    s_cbce = (fmaxf(fo, 0.0f) - fo * ctrt + log1pf(expf(-fabsf(fo)))) * posf;
  }
  __shared__ float sh[256];
  block_sum_atomic(s_pos,  acc + 1, sh);
  block_sum_atomic(s_ctr,  acc + 2, sh);
  block_sum_atomic(s_diou, acc + 3, sh);
  block_sum_atomic(s_cbce, acc + 4, sh);
}

// ---------- finalize ----------
__global__ void finalK(const double* __restrict__ acc, float* __restrict__ out) {
  double np_ = acc[1] > 1.0 ? acc[1] : 1.0;
  double dn  = acc[2] > 1e-6 ? acc[2] : 1e-6;
  out[0] = (float)(acc[0] / np_);
  out[1] = (float)(acc[3] / dn);
  out[2] = (float)(acc[4] / np_);
}

extern "C" void kernel_launch(void* const* d_in, const int* in_sizes, int n_in,
                              void* d_out, int out_size, void* d_ws, size_t ws_size,
                              hipStream_t stream) {
  (void)in_sizes; (void)n_in; (void)out_size; (void)ws_size;
  // setup_inputs dict order: cls0,bbox0,ctr0, cls1,bbox1,ctr1, ... cls4,bbox4,ctr4, gt_bboxes, gt_labels
  const float* cls[5] = {(const float*)d_in[0],  (const float*)d_in[3],  (const float*)d_in[6],
                         (const float*)d_in[9],  (const float*)d_in[12]};
  const float* bbx[5] = {(const float*)d_in[1],  (const float*)d_in[4],  (const float*)d_in[7],
                         (const float*)d_in[10], (const float*)d_in[13]};
  const float* ctr[5] = {(const float*)d_in[2],  (const float*)d_in[5],  (const float*)d_in[8],
                         (const float*)d_in[11], (const float*)d_in[14]};
  const float4* gtb = (const float4*)d_in[15];
  const int* glab = (const int*)d_in[16];

  char* ws = (char*)d_ws;
  const int NB = BATCH * N_ANCH;                 // 273024
  const size_t SEL_OFF = 64;
  const size_t A0_OFF  = SEL_OFF + (size_t)NB * 4;     // 64 + 1092096
  const size_t LAB_OFF = A0_OFF + (size_t)NB * 4;
  const size_t BT_OFF  = LAB_OFF + (size_t)NB * 4;     // 16B-aligned
  double* acc   = (double*)ws;
  int*    sel   = (int*)(ws + SEL_OFF);
  int*    a0    = (int*)(ws + A0_OFF);
  int*    labels= (int*)(ws + LAB_OFF);
  float4* btv   = (float4*)(ws + BT_OFF);

  // zero accumulators + sel
  hipMemsetAsync(d_ws, 0, SEL_OFF + (size_t)NB * 4, stream);

  dim3 gA((N_ANCH + 255) / 256, BATCH);
  phaseA<<<gA, 256, 0, stream>>>(gtb, a0);
  phaseB<<<BATCH * NGT, 256, 0, stream>>>(gtb, sel);
  phaseC<<<(NB + 255) / 256, 256, 0, stream>>>(gtb, glab, sel, a0, labels, btv);
  clsK<<<2048, 256, 0, stream>>>(cls[0], cls[1], cls[2], cls[3], cls[4], labels, acc);
  boxK<<<(NB + 255) / 256, 256, 0, stream>>>(bbx[0], bbx[1], bbx[2], bbx[3], bbx[4],
                                             ctr[0], ctr[1], ctr[2], ctr[3], ctr[4],
                                             labels, btv, acc);
  finalK<<<1, 1, 0, stream>>>(acc, (float*)d_out);
}

// Round 2
// 114.740 us; speedup vs baseline: 2.3622x; 2.3622x over previous
//
#include <hip/hip_runtime.h>
#include <math.h>
#include <limits.h>

#pragma clang fp contract(off)

#define N_ANCH 17064
#define BATCH  16
#define NGT    32
#define BG_CLS 81
#define EPSF   1e-6f

__device__ __forceinline__ float fexp2(float x){ return __builtin_amdgcn_exp2f(x); }
__device__ __forceinline__ float flog2(float x){ return __builtin_amdgcn_logf(x); }
__device__ __forceinline__ float frcp (float x){ return __builtin_amdgcn_rcpf(x); }

// ---------- geometry ----------
struct Geo { int lvl; int j; int HW; float px; float py; };

__device__ __forceinline__ Geo geom(int n) {
  Geo g;
  if (n < 12800)      { g.lvl=0; g.j=n;       g.HW=12800; g.px=(float)((g.j & 127)*8 + 4);   g.py=(float)((g.j >> 7)*8 + 4);   }
  else if (n < 16000) { g.lvl=1; g.j=n-12800; g.HW=3200;  g.px=(float)((g.j & 63)*16 + 8);   g.py=(float)((g.j >> 6)*16 + 8);  }
  else if (n < 16800) { g.lvl=2; g.j=n-16000; g.HW=800;   g.px=(float)((g.j & 31)*32 + 16);  g.py=(float)((g.j >> 5)*32 + 16); }
  else if (n < 17008) { g.lvl=3; g.j=n-16800; g.HW=208;   g.px=(float)((g.j & 15)*64 + 32);  g.py=(float)((g.j >> 4)*64 + 32); }
  else                { g.lvl=4; g.j=n-17008; g.HW=56;    g.px=(float)((g.j & 7)*128 + 64);  g.py=(float)((g.j >> 3)*128 + 64);}
  return g;
}

// ---------- min-key top-k helpers (key = 2*kl, smaller = larger overlap) ----------
__device__ __forceinline__ bool bet(float av, int ai, float bv, int bi) {
  return (av < bv) || (av == bv && ai < bi);
}

// within-thread: caller guarantees nv < v[2]; thread-local n strictly increasing,
// so strict < reproduces JAX's stable (value-desc, index-asc) tie rule.
__device__ __forceinline__ void insert3min(float* v, int* i, float nv, int ni) {
  if (nv < v[0])      { v[2]=v[1]; i[2]=i[1]; v[1]=v[0]; i[1]=i[0]; v[0]=nv; i[0]=ni; }
  else if (nv < v[1]) { v[2]=v[1]; i[2]=i[1]; v[1]=nv; i[1]=ni; }
  else                { v[2]=nv; i[2]=ni; }
}

// cross-thread merge: full index tie rule
__device__ __forceinline__ void insert3tie(float* v, int* i, float nv, int ni) {
  if (!bet(nv, ni, v[2], i[2])) return;
  if (bet(nv, ni, v[0], i[0]))      { v[2]=v[1]; i[2]=i[1]; v[1]=v[0]; i[1]=i[0]; v[0]=nv; i[0]=ni; }
  else if (bet(nv, ni, v[1], i[1])) { v[2]=v[1]; i[2]=i[1]; v[1]=nv; i[1]=ni; }
  else                              { v[2]=nv; i[2]=ni; }
}

// ---------- block reduce ----------
__device__ __forceinline__ void block_sum_atomic(float v, double* target, float* sh) {
  int t = threadIdx.x;
  sh[t] = v;
  __syncthreads();
  #pragma unroll
  for (int off = 128; off > 0; off >>= 1) {
    if (t < off) sh[t] += sh[t + off];
    __syncthreads();
  }
  if (t == 0) atomicAdd(target, (double)sh[0]);
  __syncthreads();
}

// ---------- Phase B: per-(b,g) top3 by ov1-key and top1 by ov2-key ----------
__global__ __launch_bounds__(256) void phaseB(const float4* __restrict__ gtb,
                                              int* __restrict__ sel) {
  int blk = blockIdx.x;
  int b = blk >> 5, g = blk & 31;
  float4 GB = gtb[b * NGT + g];
  int t = threadIdx.x;
  float c1x = (GB.x + GB.z) * 0.5f, c1y = (GB.y + GB.w) * 0.5f;
  float w1 = GB.z - GB.x + EPSF, h1 = GB.w - GB.y + EPSF;
  float w1s = w1 * w1, h1s = h1 * h1;
  float iw = 1.0f / w1s, ih = 1.0f / h1s;
  float iws = iw + ih;
  float Lg = logf(w1s) + logf(h1s);
  float Ay = 4.0f * ih;
  float Axc = 4.0f * iw;

  float v1[3] = {INFINITY, INFINITY, INFINITY};
  int   i1[3] = {INT_MAX, INT_MAX, INT_MAX};
  float v2 = INFINITY; int i2 = INT_MAX;

  // key = 2*kl = w2s*(iw+ih) + 4dx^2*iw + 4dy^2*ih + Lg - 2*log(w2s) - 2
  // per-thread the x-column is FIXED per level (row stride 256 wraps width).
  #define DO_LEVEL(BASE, LGW, H, STRIDE, RF) do {                               \
    const int W_ = 1 << (LGW);                                                  \
    float w2a = (RF) + 1e-6f;          float w2sa = w2a * w2a;                  \
    float w2b = (RF) * 0.9f + 1e-6f;   float w2sb = w2b * w2b;                  \
    float K1 = w2sa * iws + Lg - 2.0f * logf(w2sa) - 2.0f;                      \
    float K2 = w2sb * iws + Lg - 2.0f * logf(w2sb) - 2.0f;                      \
    int col = t & (W_ - 1);                                                     \
    float px = (float)(col * (STRIDE) + (STRIDE) / 2);                          \
    float dx = c1x - px;                                                        \
    float kx1 = Axc * dx * dx + K1;                                             \
    float kx2 = Axc * dx * dx + K2;                                             \
    int rstep = 256 >> (LGW);                                                   \
    for (int row = t >> (LGW); row < (H); row += rstep) {                       \
      float py = (float)(row * (STRIDE) + (STRIDE) / 2);                        \
      float dy = c1y - py;                                                      \
      float dy2 = dy * dy;                                                      \
      float k1 = fmaf(Ay, dy2, kx1);                                            \
      float k2 = fmaf(Ay, dy2, kx2);                                            \
      int n = (BASE) + (row << (LGW)) + col;                                    \
      if (k1 < v1[2]) insert3min(v1, i1, k1, n);                                \
      if (k2 < v2) { v2 = k2; i2 = n; }                                         \
    }                                                                           \
  } while (0)

  DO_LEVEL(0,     7, 100,   8,  45.5f);
  DO_LEVEL(12800, 6,  50,  16, 133.5f);
  DO_LEVEL(16000, 5,  25,  32, 213.5f);
  DO_LEVEL(16800, 4,  13,  64, 277.5f);
  DO_LEVEL(17008, 3,   7, 128, 405.5f);
  #undef DO_LEVEL

  __shared__ float sv[256 * 3];
  __shared__ int   si[256 * 3];
  __shared__ float tv[256];
  __shared__ int   ti[256];
  sv[t*3+0] = v1[0]; sv[t*3+1] = v1[1]; sv[t*3+2] = v1[2];
  si[t*3+0] = i1[0]; si[t*3+1] = i1[1]; si[t*3+2] = i1[2];
  tv[t] = v2; ti[t] = i2;
  __syncthreads();
  for (int off = 128; off > 0; off >>= 1) {
    if (t < off) {
      #pragma unroll
      for (int k = 0; k < 3; ++k)
        insert3tie(&sv[t * 3], &si[t * 3], sv[(t + off) * 3 + k], si[(t + off) * 3 + k]);
      if (bet(tv[t + off], ti[t + off], tv[t], ti[t])) { tv[t] = tv[t + off]; ti[t] = ti[t + off]; }
    }
    __syncthreads();
  }
  if (t == 0) {
    int base = b * N_ANCH;
    atomicMax(&sel[base + si[0]], 32 + g);   // tier1 (ov1 top3)
    atomicMax(&sel[base + si[1]], 32 + g);
    atomicMax(&sel[base + si[2]], 32 + g);
    atomicMax(&sel[base + ti[0]], 64 + g);   // tier2 (ov2 top1) beats tier1
  }
}

// ---------- fused: decode assignment -> labels ; DIoU + centerness (positives only) ----------
__global__ __launch_bounds__(256) void cboxK(
    const float4* __restrict__ gtb, const int* __restrict__ glab,
    const int* __restrict__ sel,
    const float* __restrict__ bb0, const float* __restrict__ bb1, const float* __restrict__ bb2,
    const float* __restrict__ bb3, const float* __restrict__ bb4,
    const float* __restrict__ ct0, const float* __restrict__ ct1, const float* __restrict__ ct2,
    const float* __restrict__ ct3, const float* __restrict__ ct4,
    int* __restrict__ labels, double* __restrict__ acc) {
  int idx = blockIdx.x * 256 + threadIdx.x;
  float s_pos = 0.f, s_ctr = 0.f, s_diou = 0.f, s_cbce = 0.f;
  if (idx < BATCH * N_ANCH) {
    int s = sel[idx];
    int lab = BG_CLS;
    if (s >= 32) {
      int b = idx / N_ANCH;
      int n = idx - b * N_ANCH;
      int g = s & 31;
      lab = glab[b * NGT + g];                 // always < 81 -> positive
      float4 gb = gtb[b * NGT + g];
      Geo G = geom(n);
      const float* bb; const float* ct;
      if (G.lvl == 0)      { bb = bb0; ct = ct0; }
      else if (G.lvl == 1) { bb = bb1; ct = ct1; }
      else if (G.lvl == 2) { bb = bb2; ct = ct2; }
      else if (G.lvl == 3) { bb = bb3; ct = ct3; }
      else                 { bb = bb4; ct = ct4; }
      const float* bp = bb + b * 4 * G.HW + G.j;
      float f0 = bp[0];
      float f1 = bp[G.HW];
      float f2 = bp[2 * G.HW];
      float f3 = bp[3 * G.HW];
      float fo = ct[b * G.HW + G.j];

      float tx = G.px - gb.x, ty = G.py - gb.y, tz = gb.z - G.px, tw = gb.w - G.py;

      float lr_min = fminf(tx, tz), lr_max = fmaxf(tx, tz);
      float tb_min = fminf(ty, tw), tb_max = fmaxf(ty, tw);
      float prod = (lr_min / lr_max) * (tb_min / tb_max);
      float ctrt = sqrtf(fmaxf(prod, 0.0f));

      float pb0 = G.px - f0, pb1 = G.py - f1, pb2 = G.px + f2, pb3 = G.py + f3;
      float tb0 = G.px - tx, tb1 = G.py - ty, tb2 = G.px + tz, tb3 = G.py + tw;

      float ltx = fmaxf(pb0, tb0), lty = fmaxf(pb1, tb1);
      float rbx = fminf(pb2, tb2), rby = fminf(pb3, tb3);
      float whx = fmaxf(rbx - ltx, 0.0f), why = fmaxf(rby - lty, 0.0f);
      float ovl = whx * why;
      float ap = (pb2 - pb0) * (pb3 - pb1);
      float ag = (tb2 - tb0) * (tb3 - tb1);
      float ious = ovl / (ap + ag - ovl + EPSF);
      float eltx = fminf(pb0, tb0), elty = fminf(pb1, tb1);
      float erbx = fmaxf(pb2, tb2), erby = fmaxf(pb3, tb3);
      float ewx = fmaxf(erbx - eltx, 0.0f), ewy = fmaxf(erby - elty, 0.0f);
      float c2v = ewx * ewx + ewy * ewy + EPSF;
      float sx = pb0 + pb2 - tb0 - tb2;
      float sy = pb1 + pb3 - tb1 - tb3;
      float rho2 = (sx * sx + sy * sy) * 0.25f;
      float dl = 1.0f - (ious - rho2 / c2v);

      s_pos  = 1.0f;
      s_ctr  = ctrt;
      s_diou = dl * ctrt;
      s_cbce = fmaxf(fo, 0.0f) - fo * ctrt + log1pf(expf(-fabsf(fo)));
    }
    labels[idx] = lab;
  }
  __shared__ float sh[256];
  block_sum_atomic(s_pos,  acc + 1, sh);
  block_sum_atomic(s_ctr,  acc + 2, sh);
  block_sum_atomic(s_diou, acc + 3, sh);
  block_sum_atomic(s_cbce, acc + 4, sh);
}

// ---------- focal classification loss ----------
__device__ __forceinline__ float cls_term(float x, bool tgt) {
  float ax = fabsf(x);
  float e  = fexp2(ax * -1.44269504088896340736f);   // exp(-|x|) in (0,1]
  float r  = frcp(1.0f + e);
  float p  = (x >= 0.0f) ? r : e * r;                // sigmoid(x)
  float l1pe = flog2(1.0f + e) * 0.69314718055994530942f;  // log1p(e)
  float pt = tgt ? (1.0f - p) : p;
  float fw = (tgt ? 0.25f : 0.75f) * (pt * pt);
  float bce = fmaxf(x, 0.0f) - (tgt ? x : 0.0f) + l1pe;
  return bce * fw;
}

__global__ __launch_bounds__(256) void clsK(const float* __restrict__ c0, const float* __restrict__ c1,
                                            const float* __restrict__ c2, const float* __restrict__ c3,
                                            const float* __restrict__ c4,
                                            const int* __restrict__ labels, double* __restrict__ acc) {
  constexpr int N4 = N_ANCH / 4;        // 4266
  constexpr int SLOTS = BATCH * N4;     // 68256
  int gid = blockIdx.x * 256 + threadIdx.x;
  int cs  = gid / SLOTS;                // class-strip 0..7
  int rem = gid - cs * SLOTS;
  int b   = rem / N4;
  int n4  = rem - b * N4;

  const float* base; int HW; int j;
  if (n4 < 3200)      { base = c0; HW = 12800; j = n4 << 2; }
  else if (n4 < 4000) { base = c1; HW = 3200;  j = (n4 - 3200) << 2; }
  else if (n4 < 4200) { base = c2; HW = 800;   j = (n4 - 4000) << 2; }
  else if (n4 < 4252) { base = c3; HW = 208;   j = (n4 - 4200) << 2; }
  else                { base = c4; HW = 56;    j = (n4 - 4252) << 2; }

  const float* p = base + (size_t)(b * 81) * HW + j;
  int4 l4 = *(const int4*)(labels + b * N_ANCH + (n4 << 2));
  float local = 0.0f;
  for (int c = cs; c < 81; c += 8) {
    float4 f = *(const float4*)(p + (size_t)c * HW);
    local += cls_term(f.x, c == l4.x);
    local += cls_term(f.y, c == l4.y);
    local += cls_term(f.z, c == l4.z);
    local += cls_term(f.w, c == l4.w);
  }
  __shared__ float sh[256];
  block_sum_atomic(local, acc + 0, sh);
}

// ---------- finalize ----------
__global__ void finalK(const double* __restrict__ acc, float* __restrict__ out) {
  double np_ = acc[1] > 1.0 ? acc[1] : 1.0;
  double dn  = acc[2] > 1e-6 ? acc[2] : 1e-6;
  out[0] = (float)(acc[0] / np_);
  out[1] = (float)(acc[3] / dn);
  out[2] = (float)(acc[4] / np_);
}

extern "C" void kernel_launch(void* const* d_in, const int* in_sizes, int n_in,
                              void* d_out, int out_size, void* d_ws, size_t ws_size,
                              hipStream_t stream) {
  (void)in_sizes; (void)n_in; (void)out_size; (void)ws_size;
  const float* cls[5] = {(const float*)d_in[0],  (const float*)d_in[3],  (const float*)d_in[6],
                         (const float*)d_in[9],  (const float*)d_in[12]};
  const float* bbx[5] = {(const float*)d_in[1],  (const float*)d_in[4],  (const float*)d_in[7],
                         (const float*)d_in[10], (const float*)d_in[13]};
  const float* ctr[5] = {(const float*)d_in[2],  (const float*)d_in[5],  (const float*)d_in[8],
                         (const float*)d_in[11], (const float*)d_in[14]};
  const float4* gtb = (const float4*)d_in[15];
  const int* glab = (const int*)d_in[16];

  char* ws = (char*)d_ws;
  const int NB = BATCH * N_ANCH;                   // 273024
  const size_t SEL_OFF = 64;
  const size_t LAB_OFF = SEL_OFF + (size_t)NB * 4; // 16B aligned
  double* acc    = (double*)ws;
  int*    sel    = (int*)(ws + SEL_OFF);
  int*    labels = (int*)(ws + LAB_OFF);

  // zero accumulators + sel
  hipMemsetAsync(d_ws, 0, LAB_OFF, stream);

  phaseB<<<BATCH * NGT, 256, 0, stream>>>(gtb, sel);
  cboxK<<<(NB + 255) / 256, 256, 0, stream>>>(gtb, glab, sel,
                                              bbx[0], bbx[1], bbx[2], bbx[3], bbx[4],
                                              ctr[0], ctr[1], ctr[2], ctr[3], ctr[4],
                                              labels, acc);
  clsK<<<(8 * (NB / 4)) / 256, 256, 0, stream>>>(cls[0], cls[1], cls[2], cls[3], cls[4],
                                                 labels, acc);
  finalK<<<1, 1, 0, stream>>>(acc, (float*)d_out);
}

// Round 3
// 54.947 us; speedup vs baseline: 4.9327x; 2.0882x over previous
//
#include <hip/hip_runtime.h>
#include <math.h>
#include <limits.h>

#pragma clang fp contract(off)

#define N_ANCH 17064
#define BATCH  16
#define NGT    32
#define BG_CLS 81
#define EPSF   1e-6f

#define CLS_NBLK 2133     // 8 strips * 16 * 4266 / 256
#define BOX_NBLK 256

__device__ __forceinline__ float fexp2(float x){ return __builtin_amdgcn_exp2f(x); }
__device__ __forceinline__ float flog2(float x){ return __builtin_amdgcn_logf(x); }
__device__ __forceinline__ float frcp (float x){ return __builtin_amdgcn_rcpf(x); }

// ---------- geometry ----------
struct Geo { int lvl; int j; int HW; float px; float py; };

__device__ __forceinline__ Geo geom(int n) {
  Geo g;
  if (n < 12800)      { g.lvl=0; g.j=n;       g.HW=12800; g.px=(float)((g.j & 127)*8 + 4);   g.py=(float)((g.j >> 7)*8 + 4);   }
  else if (n < 16000) { g.lvl=1; g.j=n-12800; g.HW=3200;  g.px=(float)((g.j & 63)*16 + 8);   g.py=(float)((g.j >> 6)*16 + 8);  }
  else if (n < 16800) { g.lvl=2; g.j=n-16000; g.HW=800;   g.px=(float)((g.j & 31)*32 + 16);  g.py=(float)((g.j >> 5)*32 + 16); }
  else if (n < 17008) { g.lvl=3; g.j=n-16800; g.HW=208;   g.px=(float)((g.j & 15)*64 + 32);  g.py=(float)((g.j >> 4)*64 + 32); }
  else                { g.lvl=4; g.j=n-17008; g.HW=56;    g.px=(float)((g.j & 7)*128 + 64);  g.py=(float)((g.j >> 3)*128 + 64);}
  return g;
}

// ---------- min-key top-k helpers (key = 2*kl, smaller = larger overlap) ----------
__device__ __forceinline__ bool bet(float av, int ai, float bv, int bi) {
  return (av < bv) || (av == bv && ai < bi);
}

__device__ __forceinline__ void insert3min(float* v, int* i, float nv, int ni) {
  if (nv < v[0])      { v[2]=v[1]; i[2]=i[1]; v[1]=v[0]; i[1]=i[0]; v[0]=nv; i[0]=ni; }
  else if (nv < v[1]) { v[2]=v[1]; i[2]=i[1]; v[1]=nv; i[1]=ni; }
  else                { v[2]=nv; i[2]=ni; }
}

__device__ __forceinline__ void insert3tie(float* v, int* i, float nv, int ni) {
  if (!bet(nv, ni, v[2], i[2])) return;
  if (bet(nv, ni, v[0], i[0]))      { v[2]=v[1]; i[2]=i[1]; v[1]=v[0]; i[1]=i[0]; v[0]=nv; i[0]=ni; }
  else if (bet(nv, ni, v[1], i[1])) { v[2]=v[1]; i[2]=i[1]; v[1]=nv; i[1]=ni; }
  else                              { v[2]=nv; i[2]=ni; }
}

// ---------- Phase B: per-(b,g) top3 by ov1-key and top1 by ov2-key ----------
__global__ __launch_bounds__(256) void phaseB(const float4* __restrict__ gtb,
                                              int* __restrict__ sel) {
  int blk = blockIdx.x;
  int b = blk >> 5, g = blk & 31;
  float4 GB = gtb[b * NGT + g];
  int t = threadIdx.x;
  float c1x = (GB.x + GB.z) * 0.5f, c1y = (GB.y + GB.w) * 0.5f;
  float w1 = GB.z - GB.x + EPSF, h1 = GB.w - GB.y + EPSF;
  float w1s = w1 * w1, h1s = h1 * h1;
  float iw = 1.0f / w1s, ih = 1.0f / h1s;
  float iws = iw + ih;
  float Lg = logf(w1s) + logf(h1s);
  float Ay = 4.0f * ih;
  float Axc = 4.0f * iw;

  float v1[3] = {INFINITY, INFINITY, INFINITY};
  int   i1[3] = {INT_MAX, INT_MAX, INT_MAX};
  float v2 = INFINITY; int i2 = INT_MAX;

  #define DO_LEVEL(BASE, LGW, H, STRIDE, RF) do {                               \
    const int W_ = 1 << (LGW);                                                  \
    float w2a = (RF) + 1e-6f;          float w2sa = w2a * w2a;                  \
    float w2b = (RF) * 0.9f + 1e-6f;   float w2sb = w2b * w2b;                  \
    float K1 = w2sa * iws + Lg - 2.0f * logf(w2sa) - 2.0f;                      \
    float K2 = w2sb * iws + Lg - 2.0f * logf(w2sb) - 2.0f;                      \
    int col = t & (W_ - 1);                                                     \
    float px = (float)(col * (STRIDE) + (STRIDE) / 2);                          \
    float dx = c1x - px;                                                        \
    float kx1 = Axc * dx * dx + K1;                                             \
    float kx2 = Axc * dx * dx + K2;                                             \
    int rstep = 256 >> (LGW);                                                   \
    for (int row = t >> (LGW); row < (H); row += rstep) {                       \
      float py = (float)(row * (STRIDE) + (STRIDE) / 2);                        \
      float dy = c1y - py;                                                      \
      float dy2 = dy * dy;                                                      \
      float k1 = fmaf(Ay, dy2, kx1);                                            \
      float k2 = fmaf(Ay, dy2, kx2);                                            \
      int n = (BASE) + (row << (LGW)) + col;                                    \
      if (k1 < v1[2]) insert3min(v1, i1, k1, n);                                \
      if (k2 < v2) { v2 = k2; i2 = n; }                                         \
    }                                                                           \
  } while (0)

  DO_LEVEL(0,     7, 100,   8,  45.5f);
  DO_LEVEL(12800, 6,  50,  16, 133.5f);
  DO_LEVEL(16000, 5,  25,  32, 213.5f);
  DO_LEVEL(16800, 4,  13,  64, 277.5f);
  DO_LEVEL(17008, 3,   7, 128, 405.5f);
  #undef DO_LEVEL

  __shared__ float sv[256 * 3];
  __shared__ int   si[256 * 3];
  __shared__ float tv[256];
  __shared__ int   ti[256];
  sv[t*3+0] = v1[0]; sv[t*3+1] = v1[1]; sv[t*3+2] = v1[2];
  si[t*3+0] = i1[0]; si[t*3+1] = i1[1]; si[t*3+2] = i1[2];
  tv[t] = v2; ti[t] = i2;
  __syncthreads();
  for (int off = 128; off > 0; off >>= 1) {
    if (t < off) {
      #pragma unroll
      for (int k = 0; k < 3; ++k)
        insert3tie(&sv[t * 3], &si[t * 3], sv[(t + off) * 3 + k], si[(t + off) * 3 + k]);
      if (bet(tv[t + off], ti[t + off], tv[t], ti[t])) { tv[t] = tv[t + off]; ti[t] = ti[t + off]; }
    }
    __syncthreads();
  }
  if (t == 0) {
    int base = b * N_ANCH;
    atomicMax(&sel[base + si[0]], 32 + g);   // tier1 (ov1 top3)
    atomicMax(&sel[base + si[1]], 32 + g);
    atomicMax(&sel[base + si[2]], 32 + g);
    atomicMax(&sel[base + ti[0]], 64 + g);   // tier2 (ov2 top1) beats tier1
  }
}

// ---------- box + centerness loss: grid-stride, per-block float4 partial (NO atomics) ----------
__global__ __launch_bounds__(256) void cboxK(
    const float4* __restrict__ gtb, const int* __restrict__ glab,
    const int* __restrict__ sel,
    const float* __restrict__ bb0, const float* __restrict__ bb1, const float* __restrict__ bb2,
    const float* __restrict__ bb3, const float* __restrict__ bb4,
    const float* __restrict__ ct0, const float* __restrict__ ct1, const float* __restrict__ ct2,
    const float* __restrict__ ct3, const float* __restrict__ ct4,
    float4* __restrict__ box_part) {
  int t = threadIdx.x;
  int gid = blockIdx.x * 256 + t;
  float s_pos = 0.f, s_ctr = 0.f, s_diou = 0.f, s_cbce = 0.f;
  for (int idx = gid; idx < BATCH * N_ANCH; idx += BOX_NBLK * 256) {
    int s = sel[idx];
    if (s < 32) continue;
    int b = idx / N_ANCH;
    int n = idx - b * N_ANCH;
    int g = s & 31;
    float4 gb = gtb[b * NGT + g];
    Geo G = geom(n);
    const float* bb; const float* ct;
    if (G.lvl == 0)      { bb = bb0; ct = ct0; }
    else if (G.lvl == 1) { bb = bb1; ct = ct1; }
    else if (G.lvl == 2) { bb = bb2; ct = ct2; }
    else if (G.lvl == 3) { bb = bb3; ct = ct3; }
    else                 { bb = bb4; ct = ct4; }
    const float* bp = bb + b * 4 * G.HW + G.j;
    float f0 = bp[0];
    float f1 = bp[G.HW];
    float f2 = bp[2 * G.HW];
    float f3 = bp[3 * G.HW];
    float fo = ct[b * G.HW + G.j];

    float tx = G.px - gb.x, ty = G.py - gb.y, tz = gb.z - G.px, tw = gb.w - G.py;

    float lr_min = fminf(tx, tz), lr_max = fmaxf(tx, tz);
    float tb_min = fminf(ty, tw), tb_max = fmaxf(ty, tw);
    float prod = (lr_min / lr_max) * (tb_min / tb_max);
    float ctrt = sqrtf(fmaxf(prod, 0.0f));

    float pb0 = G.px - f0, pb1 = G.py - f1, pb2 = G.px + f2, pb3 = G.py + f3;
    float tb0 = G.px - tx, tb1 = G.py - ty, tb2 = G.px + tz, tb3 = G.py + tw;

    float ltx = fmaxf(pb0, tb0), lty = fmaxf(pb1, tb1);
    float rbx = fminf(pb2, tb2), rby = fminf(pb3, tb3);
    float whx = fmaxf(rbx - ltx, 0.0f), why = fmaxf(rby - lty, 0.0f);
    float ovl = whx * why;
    float ap = (pb2 - pb0) * (pb3 - pb1);
    float ag = (tb2 - tb0) * (tb3 - tb1);
    float ious = ovl / (ap + ag - ovl + EPSF);
    float eltx = fminf(pb0, tb0), elty = fminf(pb1, tb1);
    float erbx = fmaxf(pb2, tb2), erby = fmaxf(pb3, tb3);
    float ewx = fmaxf(erbx - eltx, 0.0f), ewy = fmaxf(erby - elty, 0.0f);
    float c2v = ewx * ewx + ewy * ewy + EPSF;
    float sx = pb0 + pb2 - tb0 - tb2;
    float sy = pb1 + pb3 - tb1 - tb3;
    float rho2 = (sx * sx + sy * sy) * 0.25f;
    float dl = 1.0f - (ious - rho2 / c2v);

    s_pos  += 1.0f;
    s_ctr  += ctrt;
    s_diou += dl * ctrt;
    s_cbce += fmaxf(fo, 0.0f) - fo * ctrt + log1pf(expf(-fabsf(fo)));
  }
  __shared__ float4 sh4[256];
  sh4[t] = make_float4(s_pos, s_ctr, s_diou, s_cbce);
  __syncthreads();
  #pragma unroll
  for (int off = 128; off > 0; off >>= 1) {
    if (t < off) {
      float4 a = sh4[t], c = sh4[t + off];
      sh4[t] = make_float4(a.x + c.x, a.y + c.y, a.z + c.z, a.w + c.w);
    }
    __syncthreads();
  }
  if (t == 0) box_part[blockIdx.x] = sh4[0];
}

// ---------- focal classification loss: per-block float partial (NO atomics) ----------
__device__ __forceinline__ float cls_term(float x, bool tgt) {
  float ax = fabsf(x);
  float e  = fexp2(ax * -1.44269504088896340736f);   // exp(-|x|)
  float r  = frcp(1.0f + e);
  float p  = (x >= 0.0f) ? r : e * r;                // sigmoid(x)
  float l1pe = flog2(1.0f + e) * 0.69314718055994530942f;
  float pt = tgt ? (1.0f - p) : p;
  float fw = (tgt ? 0.25f : 0.75f) * (pt * pt);
  float bce = fmaxf(x, 0.0f) - (tgt ? x : 0.0f) + l1pe;
  return bce * fw;
}

__global__ __launch_bounds__(256) void clsK(const float* __restrict__ c0, const float* __restrict__ c1,
                                            const float* __restrict__ c2, const float* __restrict__ c3,
                                            const float* __restrict__ c4,
                                            const int* __restrict__ sel, const int* __restrict__ glab,
                                            float* __restrict__ cls_part) {
  constexpr int N4 = N_ANCH / 4;        // 4266
  constexpr int SLOTS = BATCH * N4;     // 68256
  int t = threadIdx.x;
  int gid = blockIdx.x * 256 + t;
  int cs  = gid / SLOTS;                // class-strip 0..7
  int rem = gid - cs * SLOTS;
  int b   = rem / N4;
  int n4  = rem - b * N4;

  const float* base; int HW; int j;
  if (n4 < 3200)      { base = c0; HW = 12800; j = n4 << 2; }
  else if (n4 < 4000) { base = c1; HW = 3200;  j = (n4 - 3200) << 2; }
  else if (n4 < 4200) { base = c2; HW = 800;   j = (n4 - 4000) << 2; }
  else if (n4 < 4252) { base = c3; HW = 208;   j = (n4 - 4200) << 2; }
  else                { base = c4; HW = 56;    j = (n4 - 4252) << 2; }

  const float* p = base + (size_t)(b * 81) * HW + j;
  int4 s4 = *(const int4*)(sel + b * N_ANCH + (n4 << 2));
  const int* gl = glab + b * NGT;
  int lx = (s4.x >= 32) ? gl[s4.x & 31] : BG_CLS;
  int ly = (s4.y >= 32) ? gl[s4.y & 31] : BG_CLS;
  int lz = (s4.z >= 32) ? gl[s4.z & 31] : BG_CLS;
  int lw = (s4.w >= 32) ? gl[s4.w & 31] : BG_CLS;

  float local = 0.0f;
  for (int c = cs; c < 81; c += 8) {
    float4 f = *(const float4*)(p + (size_t)c * HW);
    local += cls_term(f.x, c == lx);
    local += cls_term(f.y, c == ly);
    local += cls_term(f.z, c == lz);
    local += cls_term(f.w, c == lw);
  }
  __shared__ float sh[256];
  sh[t] = local;
  __syncthreads();
  #pragma unroll
  for (int off = 128; off > 0; off >>= 1) {
    if (t < off) sh[t] += sh[t + off];
    __syncthreads();
  }
  if (t == 0) cls_part[blockIdx.x] = sh[0];
}

// ---------- finalize: reduce partials, compute 3 outputs ----------
__global__ __launch_bounds__(256) void finalK(const float* __restrict__ cls_part,
                                              const float4* __restrict__ box_part,
                                              float* __restrict__ out) {
  int t = threadIdx.x;
  double c = 0.0;
  for (int i = t; i < CLS_NBLK; i += 256) c += (double)cls_part[i];
  float4 bp = box_part[t];            // exactly BOX_NBLK==256 entries
  __shared__ double sc[256];
  __shared__ double s0[256], s1[256], s2[256], s3[256];
  sc[t] = c;
  s0[t] = (double)bp.x; s1[t] = (double)bp.y; s2[t] = (double)bp.z; s3[t] = (double)bp.w;
  __syncthreads();
  #pragma unroll
  for (int off = 128; off > 0; off >>= 1) {
    if (t < off) {
      sc[t] += sc[t + off];
      s0[t] += s0[t + off]; s1[t] += s1[t + off];
      s2[t] += s2[t + off]; s3[t] += s3[t + off];
    }
    __syncthreads();
  }
  if (t == 0) {
    double np_ = s0[0] > 1.0 ? s0[0] : 1.0;
    double dn  = s1[0] > 1e-6 ? s1[0] : 1e-6;
    out[0] = (float)(sc[0] / np_);
    out[1] = (float)(s2[0] / dn);
    out[2] = (float)(s3[0] / np_);
  }
}

extern "C" void kernel_launch(void* const* d_in, const int* in_sizes, int n_in,
                              void* d_out, int out_size, void* d_ws, size_t ws_size,
                              hipStream_t stream) {
  (void)in_sizes; (void)n_in; (void)out_size; (void)ws_size;
  const float* cls[5] = {(const float*)d_in[0],  (const float*)d_in[3],  (const float*)d_in[6],
                         (const float*)d_in[9],  (const float*)d_in[12]};
  const float* bbx[5] = {(const float*)d_in[1],  (const float*)d_in[4],  (const float*)d_in[7],
                         (const float*)d_in[10], (const float*)d_in[13]};
  const float* ctr[5] = {(const float*)d_in[2],  (const float*)d_in[5],  (const float*)d_in[8],
                         (const float*)d_in[11], (const float*)d_in[14]};
  const float4* gtb = (const float4*)d_in[15];
  const int* glab = (const int*)d_in[16];

  char* ws = (char*)d_ws;
  const int NB = BATCH * N_ANCH;                       // 273024
  int*    sel      = (int*)ws;                         // NB ints (memset 0)
  const size_t CLS_OFF = (size_t)NB * 4;               // 1,092,096 (16B aligned)
  const size_t BOX_OFF = CLS_OFF + ((CLS_NBLK * 4 + 15) & ~15ul);
  float*  cls_part = (float*)(ws + CLS_OFF);
  float4* box_part = (float4*)(ws + BOX_OFF);

  hipMemsetAsync(ws, 0, (size_t)NB * 4, stream);

  phaseB<<<BATCH * NGT, 256, 0, stream>>>(gtb, sel);
  cboxK<<<BOX_NBLK, 256, 0, stream>>>(gtb, glab, sel,
                                      bbx[0], bbx[1], bbx[2], bbx[3], bbx[4],
                                      ctr[0], ctr[1], ctr[2], ctr[3], ctr[4],
                                      box_part);
  clsK<<<CLS_NBLK, 256, 0, stream>>>(cls[0], cls[1], cls[2], cls[3], cls[4],
                                     sel, glab, cls_part);
  finalK<<<1, 256, 0, stream>>>(cls_part, box_part, (float*)d_out);
}

// Round 4
// 54.006 us; speedup vs baseline: 5.0187x; 1.0174x over previous
//
#include <hip/hip_runtime.h>
#include <math.h>
#include <limits.h>

#pragma clang fp contract(off)

#define N_ANCH 17064
#define BATCH  16
#define NGT    32
#define BG_CLS 81
#define EPSF   1e-6f

#define CLS_NBLK 2133     // 8 strips * 16 * 4266 / 256
#define BOX_NBLK 256

__device__ __forceinline__ float fexp2(float x){ return __builtin_amdgcn_exp2f(x); }
__device__ __forceinline__ float flog2(float x){ return __builtin_amdgcn_logf(x); }
__device__ __forceinline__ float frcp (float x){ return __builtin_amdgcn_rcpf(x); }

// ---------- geometry ----------
struct Geo { int lvl; int j; int HW; float px; float py; };

__device__ __forceinline__ Geo geom(int n) {
  Geo g;
  if (n < 12800)      { g.lvl=0; g.j=n;       g.HW=12800; g.px=(float)((g.j & 127)*8 + 4);   g.py=(float)((g.j >> 7)*8 + 4);   }
  else if (n < 16000) { g.lvl=1; g.j=n-12800; g.HW=3200;  g.px=(float)((g.j & 63)*16 + 8);   g.py=(float)((g.j >> 6)*16 + 8);  }
  else if (n < 16800) { g.lvl=2; g.j=n-16000; g.HW=800;   g.px=(float)((g.j & 31)*32 + 16);  g.py=(float)((g.j >> 5)*32 + 16); }
  else if (n < 17008) { g.lvl=3; g.j=n-16800; g.HW=208;   g.px=(float)((g.j & 15)*64 + 32);  g.py=(float)((g.j >> 4)*64 + 32); }
  else                { g.lvl=4; g.j=n-17008; g.HW=56;    g.px=(float)((g.j & 7)*128 + 64);  g.py=(float)((g.j >> 3)*128 + 64);}
  return g;
}

// ---------- min-key top-k helpers (key = 2*kl, smaller = larger overlap) ----------
__device__ __forceinline__ bool bet(float av, int ai, float bv, int bi) {
  return (av < bv) || (av == bv && ai < bi);
}

__device__ __forceinline__ void insert3min(float* v, int* i, float nv, int ni) {
  if (nv < v[0])      { v[2]=v[1]; i[2]=i[1]; v[1]=v[0]; i[1]=i[0]; v[0]=nv; i[0]=ni; }
  else if (nv < v[1]) { v[2]=v[1]; i[2]=i[1]; v[1]=nv; i[1]=ni; }
  else                { v[2]=nv; i[2]=ni; }
}

__device__ __forceinline__ void insert3tie(float* v, int* i, float nv, int ni) {
  if (!bet(nv, ni, v[2], i[2])) return;
  if (bet(nv, ni, v[0], i[0]))      { v[2]=v[1]; i[2]=i[1]; v[1]=v[0]; i[1]=i[0]; v[0]=nv; i[0]=ni; }
  else if (bet(nv, ni, v[1], i[1])) { v[2]=v[1]; i[2]=i[1]; v[1]=nv; i[1]=ni; }
  else                              { v[2]=nv; i[2]=ni; }
}

// ---------- zero the sel array (replaces pathologically slow hipMemsetAsync fill) ----------
__global__ __launch_bounds__(256) void zeroK(int4* __restrict__ sel4) {
  int i = blockIdx.x * 256 + threadIdx.x;
  if (i < (BATCH * N_ANCH) / 4) sel4[i] = make_int4(0, 0, 0, 0);
}

// ---------- Phase B: per-(b,g) top3 by ov1-key and top1 by ov2-key ----------
__global__ __launch_bounds__(256) void phaseB(const float4* __restrict__ gtb,
                                              int* __restrict__ sel) {
  int blk = blockIdx.x;
  int b = blk >> 5, g = blk & 31;
  float4 GB = gtb[b * NGT + g];
  int t = threadIdx.x;
  float c1x = (GB.x + GB.z) * 0.5f, c1y = (GB.y + GB.w) * 0.5f;
  float w1 = GB.z - GB.x + EPSF, h1 = GB.w - GB.y + EPSF;
  float w1s = w1 * w1, h1s = h1 * h1;
  float iw = 1.0f / w1s, ih = 1.0f / h1s;
  float iws = iw + ih;
  float Lg = logf(w1s) + logf(h1s);
  float Ay = 4.0f * ih;
  float Axc = 4.0f * iw;

  float v1[3] = {INFINITY, INFINITY, INFINITY};
  int   i1[3] = {INT_MAX, INT_MAX, INT_MAX};
  float v2 = INFINITY; int i2 = INT_MAX;

  #define DO_LEVEL(BASE, LGW, H, STRIDE, RF) do {                               \
    const int W_ = 1 << (LGW);                                                  \
    float w2a = (RF) + 1e-6f;          float w2sa = w2a * w2a;                  \
    float w2b = (RF) * 0.9f + 1e-6f;   float w2sb = w2b * w2b;                  \
    float K1 = w2sa * iws + Lg - 2.0f * logf(w2sa) - 2.0f;                      \
    float K2 = w2sb * iws + Lg - 2.0f * logf(w2sb) - 2.0f;                      \
    int col = t & (W_ - 1);                                                     \
    float px = (float)(col * (STRIDE) + (STRIDE) / 2);                          \
    float dx = c1x - px;                                                        \
    float kx1 = Axc * dx * dx + K1;                                             \
    float kx2 = Axc * dx * dx + K2;                                             \
    int rstep = 256 >> (LGW);                                                   \
    for (int row = t >> (LGW); row < (H); row += rstep) {                       \
      float py = (float)(row * (STRIDE) + (STRIDE) / 2);                        \
      float dy = c1y - py;                                                      \
      float dy2 = dy * dy;                                                      \
      float k1 = fmaf(Ay, dy2, kx1);                                            \
      float k2 = fmaf(Ay, dy2, kx2);                                            \
      int n = (BASE) + (row << (LGW)) + col;                                    \
      if (k1 < v1[2]) insert3min(v1, i1, k1, n);                                \
      if (k2 < v2) { v2 = k2; i2 = n; }                                         \
    }                                                                           \
  } while (0)

  DO_LEVEL(0,     7, 100,   8,  45.5f);
  DO_LEVEL(12800, 6,  50,  16, 133.5f);
  DO_LEVEL(16000, 5,  25,  32, 213.5f);
  DO_LEVEL(16800, 4,  13,  64, 277.5f);
  DO_LEVEL(17008, 3,   7, 128, 405.5f);
  #undef DO_LEVEL

  __shared__ float sv[256 * 3];
  __shared__ int   si[256 * 3];
  __shared__ float tv[256];
  __shared__ int   ti[256];
  sv[t*3+0] = v1[0]; sv[t*3+1] = v1[1]; sv[t*3+2] = v1[2];
  si[t*3+0] = i1[0]; si[t*3+1] = i1[1]; si[t*3+2] = i1[2];
  tv[t] = v2; ti[t] = i2;
  __syncthreads();
  for (int off = 128; off > 0; off >>= 1) {
    if (t < off) {
      #pragma unroll
      for (int k = 0; k < 3; ++k)
        insert3tie(&sv[t * 3], &si[t * 3], sv[(t + off) * 3 + k], si[(t + off) * 3 + k]);
      if (bet(tv[t + off], ti[t + off], tv[t], ti[t])) { tv[t] = tv[t + off]; ti[t] = ti[t + off]; }
    }
    __syncthreads();
  }
  if (t == 0) {
    int base = b * N_ANCH;
    atomicMax(&sel[base + si[0]], 32 + g);   // tier1 (ov1 top3)
    atomicMax(&sel[base + si[1]], 32 + g);
    atomicMax(&sel[base + si[2]], 32 + g);
    atomicMax(&sel[base + ti[0]], 64 + g);   // tier2 (ov2 top1) beats tier1
  }
}

// ---------- box + centerness loss: grid-stride, per-block float4 partial (NO atomics) ----------
__global__ __launch_bounds__(256) void cboxK(
    const float4* __restrict__ gtb, const int* __restrict__ glab,
    const int* __restrict__ sel,
    const float* __restrict__ bb0, const float* __restrict__ bb1, const float* __restrict__ bb2,
    const float* __restrict__ bb3, const float* __restrict__ bb4,
    const float* __restrict__ ct0, const float* __restrict__ ct1, const float* __restrict__ ct2,
    const float* __restrict__ ct3, const float* __restrict__ ct4,
    float4* __restrict__ box_part) {
  int t = threadIdx.x;
  int gid = blockIdx.x * 256 + t;
  float s_pos = 0.f, s_ctr = 0.f, s_diou = 0.f, s_cbce = 0.f;
  for (int idx = gid; idx < BATCH * N_ANCH; idx += BOX_NBLK * 256) {
    int s = sel[idx];
    if (s < 32) continue;
    int b = idx / N_ANCH;
    int n = idx - b * N_ANCH;
    int g = s & 31;
    float4 gb = gtb[b * NGT + g];
    Geo G = geom(n);
    const float* bb; const float* ct;
    if (G.lvl == 0)      { bb = bb0; ct = ct0; }
    else if (G.lvl == 1) { bb = bb1; ct = ct1; }
    else if (G.lvl == 2) { bb = bb2; ct = ct2; }
    else if (G.lvl == 3) { bb = bb3; ct = ct3; }
    else                 { bb = bb4; ct = ct4; }
    const float* bp = bb + b * 4 * G.HW + G.j;
    float f0 = bp[0];
    float f1 = bp[G.HW];
    float f2 = bp[2 * G.HW];
    float f3 = bp[3 * G.HW];
    float fo = ct[b * G.HW + G.j];

    float tx = G.px - gb.x, ty = G.py - gb.y, tz = gb.z - G.px, tw = gb.w - G.py;

    float lr_min = fminf(tx, tz), lr_max = fmaxf(tx, tz);
    float tb_min = fminf(ty, tw), tb_max = fmaxf(ty, tw);
    float prod = (lr_min / lr_max) * (tb_min / tb_max);
    float ctrt = sqrtf(fmaxf(prod, 0.0f));

    float pb0 = G.px - f0, pb1 = G.py - f1, pb2 = G.px + f2, pb3 = G.py + f3;
    float tb0 = G.px - tx, tb1 = G.py - ty, tb2 = G.px + tz, tb3 = G.py + tw;

    float ltx = fmaxf(pb0, tb0), lty = fmaxf(pb1, tb1);
    float rbx = fminf(pb2, tb2), rby = fminf(pb3, tb3);
    float whx = fmaxf(rbx - ltx, 0.0f), why = fmaxf(rby - lty, 0.0f);
    float ovl = whx * why;
    float ap = (pb2 - pb0) * (pb3 - pb1);
    float ag = (tb2 - tb0) * (tb3 - tb1);
    float ious = ovl / (ap + ag - ovl + EPSF);
    float eltx = fminf(pb0, tb0), elty = fminf(pb1, tb1);
    float erbx = fmaxf(pb2, tb2), erby = fmaxf(pb3, tb3);
    float ewx = fmaxf(erbx - eltx, 0.0f), ewy = fmaxf(erby - elty, 0.0f);
    float c2v = ewx * ewx + ewy * ewy + EPSF;
    float sx = pb0 + pb2 - tb0 - tb2;
    float sy = pb1 + pb3 - tb1 - tb3;
    float rho2 = (sx * sx + sy * sy) * 0.25f;
    float dl = 1.0f - (ious - rho2 / c2v);

    s_pos  += 1.0f;
    s_ctr  += ctrt;
    s_diou += dl * ctrt;
    s_cbce += fmaxf(fo, 0.0f) - fo * ctrt + log1pf(expf(-fabsf(fo)));
  }
  __shared__ float4 sh4[256];
  sh4[t] = make_float4(s_pos, s_ctr, s_diou, s_cbce);
  __syncthreads();
  #pragma unroll
  for (int off = 128; off > 0; off >>= 1) {
    if (t < off) {
      float4 a = sh4[t], c = sh4[t + off];
      sh4[t] = make_float4(a.x + c.x, a.y + c.y, a.z + c.z, a.w + c.w);
    }
    __syncthreads();
  }
  if (t == 0) box_part[blockIdx.x] = sh4[0];
}

// ---------- focal classification loss: per-block float partial (NO atomics) ----------
__device__ __forceinline__ float cls_term(float x, bool tgt) {
  float ax = fabsf(x);
  float e  = fexp2(ax * -1.44269504088896340736f);   // exp(-|x|)
  float r  = frcp(1.0f + e);
  float p  = (x >= 0.0f) ? r : e * r;                // sigmoid(x)
  float l1pe = flog2(1.0f + e) * 0.69314718055994530942f;
  float pt = tgt ? (1.0f - p) : p;
  float fw = (tgt ? 0.25f : 0.75f) * (pt * pt);
  float bce = fmaxf(x, 0.0f) - (tgt ? x : 0.0f) + l1pe;
  return bce * fw;
}

__global__ __launch_bounds__(256) void clsK(const float* __restrict__ c0, const float* __restrict__ c1,
                                            const float* __restrict__ c2, const float* __restrict__ c3,
                                            const float* __restrict__ c4,
                                            const int* __restrict__ sel, const int* __restrict__ glab,
                                            float* __restrict__ cls_part) {
  constexpr int N4 = N_ANCH / 4;        // 4266
  constexpr int SLOTS = BATCH * N4;     // 68256
  int t = threadIdx.x;
  int gid = blockIdx.x * 256 + t;
  int cs  = gid / SLOTS;                // class-strip 0..7
  int rem = gid - cs * SLOTS;
  int b   = rem / N4;
  int n4  = rem - b * N4;

  const float* base; int HW; int j;
  if (n4 < 3200)      { base = c0; HW = 12800; j = n4 << 2; }
  else if (n4 < 4000) { base = c1; HW = 3200;  j = (n4 - 3200) << 2; }
  else if (n4 < 4200) { base = c2; HW = 800;   j = (n4 - 4000) << 2; }
  else if (n4 < 4252) { base = c3; HW = 208;   j = (n4 - 4200) << 2; }
  else                { base = c4; HW = 56;    j = (n4 - 4252) << 2; }

  const float* p = base + (size_t)(b * 81) * HW + j;
  int4 s4 = *(const int4*)(sel + b * N_ANCH + (n4 << 2));
  const int* gl = glab + b * NGT;
  int lx = (s4.x >= 32) ? gl[s4.x & 31] : BG_CLS;
  int ly = (s4.y >= 32) ? gl[s4.y & 31] : BG_CLS;
  int lz = (s4.z >= 32) ? gl[s4.z & 31] : BG_CLS;
  int lw = (s4.w >= 32) ? gl[s4.w & 31] : BG_CLS;

  float local = 0.0f;
  for (int c = cs; c < 81; c += 8) {
    float4 f = *(const float4*)(p + (size_t)c * HW);
    local += cls_term(f.x, c == lx);
    local += cls_term(f.y, c == ly);
    local += cls_term(f.z, c == lz);
    local += cls_term(f.w, c == lw);
  }
  __shared__ float sh[256];
  sh[t] = local;
  __syncthreads();
  #pragma unroll
  for (int off = 128; off > 0; off >>= 1) {
    if (t < off) sh[t] += sh[t + off];
    __syncthreads();
  }
  if (t == 0) cls_part[blockIdx.x] = sh[0];
}

// ---------- finalize: reduce partials, compute 3 outputs ----------
__global__ __launch_bounds__(256) void finalK(const float* __restrict__ cls_part,
                                              const float4* __restrict__ box_part,
                                              float* __restrict__ out) {
  int t = threadIdx.x;
  double c = 0.0;
  for (int i = t; i < CLS_NBLK; i += 256) c += (double)cls_part[i];
  float4 bp = box_part[t];            // exactly BOX_NBLK==256 entries
  __shared__ double sc[256];
  __shared__ double s0[256], s1[256], s2[256], s3[256];
  sc[t] = c;
  s0[t] = (double)bp.x; s1[t] = (double)bp.y; s2[t] = (double)bp.z; s3[t] = (double)bp.w;
  __syncthreads();
  #pragma unroll
  for (int off = 128; off > 0; off >>= 1) {
    if (t < off) {
      sc[t] += sc[t + off];
      s0[t] += s0[t + off]; s1[t] += s1[t + off];
      s2[t] += s2[t + off]; s3[t] += s3[t + off];
    }
    __syncthreads();
  }
  if (t == 0) {
    double np_ = s0[0] > 1.0 ? s0[0] : 1.0;
    double dn  = s1[0] > 1e-6 ? s1[0] : 1e-6;
    out[0] = (float)(sc[0] / np_);
    out[1] = (float)(s2[0] / dn);
    out[2] = (float)(s3[0] / np_);
  }
}

extern "C" void kernel_launch(void* const* d_in, const int* in_sizes, int n_in,
                              void* d_out, int out_size, void* d_ws, size_t ws_size,
                              hipStream_t stream) {
  (void)in_sizes; (void)n_in; (void)out_size; (void)ws_size;
  const float* cls[5] = {(const float*)d_in[0],  (const float*)d_in[3],  (const float*)d_in[6],
                         (const float*)d_in[9],  (const float*)d_in[12]};
  const float* bbx[5] = {(const float*)d_in[1],  (const float*)d_in[4],  (const float*)d_in[7],
                         (const float*)d_in[10], (const float*)d_in[13]};
  const float* ctr[5] = {(const float*)d_in[2],  (const float*)d_in[5],  (const float*)d_in[8],
                         (const float*)d_in[11], (const float*)d_in[14]};
  const float4* gtb = (const float4*)d_in[15];
  const int* glab = (const int*)d_in[16];

  char* ws = (char*)d_ws;
  const int NB = BATCH * N_ANCH;                       // 273024
  int*    sel      = (int*)ws;                         // NB ints
  const size_t CLS_OFF = (size_t)NB * 4;               // 1,092,096 (16B aligned)
  const size_t BOX_OFF = CLS_OFF + ((CLS_NBLK * 4 + 15) & ~15ul);
  float*  cls_part = (float*)(ws + CLS_OFF);
  float4* box_part = (float4*)(ws + BOX_OFF);

  zeroK<<<(NB / 4 + 255) / 256, 256, 0, stream>>>((int4*)sel);
  phaseB<<<BATCH * NGT, 256, 0, stream>>>(gtb, sel);
  cboxK<<<BOX_NBLK, 256, 0, stream>>>(gtb, glab, sel,
                                      bbx[0], bbx[1], bbx[2], bbx[3], bbx[4],
                                      ctr[0], ctr[1], ctr[2], ctr[3], ctr[4],
                                      box_part);
  clsK<<<CLS_NBLK, 256, 0, stream>>>(cls[0], cls[1], cls[2], cls[3], cls[4],
                                     sel, glab, cls_part);
  finalK<<<1, 256, 0, stream>>>(cls_part, box_part, (float*)d_out);
}

// Round 5
// 42.795 us; speedup vs baseline: 6.3335x; 1.2620x over previous
//
#include <hip/hip_runtime.h>
#include <math.h>
#include <limits.h>

#pragma clang fp contract(off)

#define N_ANCH 17064
#define BATCH  16
#define NGT    32
#define BG_CLS 81
#define EPSF   1e-6f

#define NPB     512          // phaseB blocks (16*32)
#define NSTREAM 2048         // stream blocks
#define L2E 1.44269504088896340736f
#define LN2 0.69314718055994530942f

// float4 counts per level (16*81*HW/4) and cumulative bounds
#define F4_0 4147200
#define C1   4147200
#define C2   5184000
#define C3   5443200
#define C4   5510592
#define TOT4 5528736

__device__ __forceinline__ float fexp2(float x){ return __builtin_amdgcn_exp2f(x); }
__device__ __forceinline__ float flog2(float x){ return __builtin_amdgcn_logf(x); }
__device__ __forceinline__ float frcp (float x){ return __builtin_amdgcn_rcpf(x); }

// ---------- geometry ----------
struct Geo { int lvl; int j; int HW; float px; float py; };

__device__ __forceinline__ Geo geom(int n) {
  Geo g;
  if (n < 12800)      { g.lvl=0; g.j=n;       g.HW=12800; g.px=(float)((g.j & 127)*8 + 4);   g.py=(float)((g.j >> 7)*8 + 4);   }
  else if (n < 16000) { g.lvl=1; g.j=n-12800; g.HW=3200;  g.px=(float)((g.j & 63)*16 + 8);   g.py=(float)((g.j >> 6)*16 + 8);  }
  else if (n < 16800) { g.lvl=2; g.j=n-16000; g.HW=800;   g.px=(float)((g.j & 31)*32 + 16);  g.py=(float)((g.j >> 5)*32 + 16); }
  else if (n < 17008) { g.lvl=3; g.j=n-16800; g.HW=208;   g.px=(float)((g.j & 15)*64 + 32);  g.py=(float)((g.j >> 4)*64 + 32); }
  else                { g.lvl=4; g.j=n-17008; g.HW=56;    g.px=(float)((g.j & 7)*128 + 64);  g.py=(float)((g.j >> 3)*128 + 64);}
  return g;
}

// ---------- min-key top-k helpers (key = 2*kl, smaller = larger overlap) ----------
__device__ __forceinline__ bool bet(float av, int ai, float bv, int bi) {
  return (av < bv) || (av == bv && ai < bi);
}

__device__ __forceinline__ void insert3min(float* v, int* i, float nv, int ni) {
  if (nv < v[0])      { v[2]=v[1]; i[2]=i[1]; v[1]=v[0]; i[1]=i[0]; v[0]=nv; i[0]=ni; }
  else if (nv < v[1]) { v[2]=v[1]; i[2]=i[1]; v[1]=nv; i[1]=ni; }
  else                { v[2]=nv; i[2]=ni; }
}

__device__ __forceinline__ void insert3tie(float* v, int* i, float nv, int ni) {
  if (!bet(nv, ni, v[2], i[2])) return;
  if (bet(nv, ni, v[0], i[0]))      { v[2]=v[1]; i[2]=i[1]; v[1]=v[0]; i[1]=i[0]; v[0]=nv; i[0]=ni; }
  else if (bet(nv, ni, v[1], i[1])) { v[2]=v[1]; i[2]=i[1]; v[1]=nv; i[1]=ni; }
  else                              { v[2]=nv; i[2]=ni; }
}

// negative-class focal term: 0.75 * sigmoid(x)^2 * softplus(x)
__device__ __forceinline__ float negterm(float x) {
  float ax = fabsf(x);
  float e  = fexp2(ax * -L2E);          // exp(-|x|)
  float r  = frcp(1.0f + e);
  float p  = (x >= 0.0f) ? r : e * r;   // sigmoid(x)
  float sp = fmaxf(x, 0.0f) + flog2(1.0f + e) * LN2;   // softplus(x)
  return 0.75f * (p * p) * sp;
}

// ---------- megaK: heterogeneous grid ----------
// blocks [0, NPB):          per-(b,g) top3(ov1) + top1(ov2) -> win[]
// blocks [NPB, NPB+NSTREAM): label-free stream of all cls logits -> part[]
__global__ __launch_bounds__(256) void megaK(const float4* __restrict__ gtb,
                                             const float4* __restrict__ s0,
                                             const float4* __restrict__ s1,
                                             const float4* __restrict__ s2,
                                             const float4* __restrict__ s3,
                                             const float4* __restrict__ s4,
                                             int4* __restrict__ win,
                                             float* __restrict__ part) {
  __shared__ float sv[256 * 3];
  __shared__ int   si[256 * 3];
  __shared__ float tv[256];
  __shared__ int   ti[256];
  __shared__ float sh[256];

  int t = threadIdx.x;
  if (blockIdx.x < NPB) {
    // ---------------- phaseB ----------------
    int blk = blockIdx.x;
    int b = blk >> 5, g = blk & 31;
    float4 GB = gtb[b * NGT + g];
    float c1x = (GB.x + GB.z) * 0.5f, c1y = (GB.y + GB.w) * 0.5f;
    float w1 = GB.z - GB.x + EPSF, h1 = GB.w - GB.y + EPSF;
    float w1s = w1 * w1, h1s = h1 * h1;
    float iw = 1.0f / w1s, ih = 1.0f / h1s;
    float iws = iw + ih;
    float Lg = logf(w1s) + logf(h1s);
    float Ay = 4.0f * ih;
    float Axc = 4.0f * iw;

    float v1[3] = {INFINITY, INFINITY, INFINITY};
    int   i1[3] = {INT_MAX, INT_MAX, INT_MAX};
    float v2 = INFINITY; int i2 = INT_MAX;

    #define DO_LEVEL(BASE, LGW, H, STRIDE, RF) do {                             \
      const int W_ = 1 << (LGW);                                                \
      float w2a = (RF) + 1e-6f;          float w2sa = w2a * w2a;                \
      float w2b = (RF) * 0.9f + 1e-6f;   float w2sb = w2b * w2b;                \
      float K1 = w2sa * iws + Lg - 2.0f * logf(w2sa) - 2.0f;                    \
      float K2 = w2sb * iws + Lg - 2.0f * logf(w2sb) - 2.0f;                    \
      int col = t & (W_ - 1);                                                   \
      float px = (float)(col * (STRIDE) + (STRIDE) / 2);                        \
      float dx = c1x - px;                                                      \
      float kx1 = Axc * dx * dx + K1;                                           \
      float kx2 = Axc * dx * dx + K2;                                           \
      int rstep = 256 >> (LGW);                                                 \
      for (int row = t >> (LGW); row < (H); row += rstep) {                     \
        float py = (float)(row * (STRIDE) + (STRIDE) / 2);                      \
        float dy = c1y - py;                                                    \
        float dy2 = dy * dy;                                                    \
        float k1 = fmaf(Ay, dy2, kx1);                                          \
        float k2 = fmaf(Ay, dy2, kx2);                                          \
        int n = (BASE) + (row << (LGW)) + col;                                  \
        if (k1 < v1[2]) insert3min(v1, i1, k1, n);                              \
        if (k2 < v2) { v2 = k2; i2 = n; }                                       \
      }                                                                         \
    } while (0)

    DO_LEVEL(0,     7, 100,   8,  45.5f);
    DO_LEVEL(12800, 6,  50,  16, 133.5f);
    DO_LEVEL(16000, 5,  25,  32, 213.5f);
    DO_LEVEL(16800, 4,  13,  64, 277.5f);
    DO_LEVEL(17008, 3,   7, 128, 405.5f);
    #undef DO_LEVEL

    sv[t*3+0] = v1[0]; sv[t*3+1] = v1[1]; sv[t*3+2] = v1[2];
    si[t*3+0] = i1[0]; si[t*3+1] = i1[1]; si[t*3+2] = i1[2];
    tv[t] = v2; ti[t] = i2;
    __syncthreads();
    for (int off = 128; off > 0; off >>= 1) {
      if (t < off) {
        #pragma unroll
        for (int k = 0; k < 3; ++k)
          insert3tie(&sv[t * 3], &si[t * 3], sv[(t + off) * 3 + k], si[(t + off) * 3 + k]);
        if (bet(tv[t + off], ti[t + off], tv[t], ti[t])) { tv[t] = tv[t + off]; ti[t] = ti[t + off]; }
      }
      __syncthreads();
    }
    if (t == 0) win[blk] = make_int4(si[0], si[1], si[2], ti[0]);
  } else {
    // ---------------- label-free cls stream ----------------
    int sb = blockIdx.x - NPB;
    float local = 0.0f;
    for (int i = sb * 256 + t; i < TOT4; i += NSTREAM * 256) {
      const float4* p; int off;
      if (i < C1)      { p = s0; off = i; }
      else if (i < C2) { p = s1; off = i - C1; }
      else if (i < C3) { p = s2; off = i - C2; }
      else if (i < C4) { p = s3; off = i - C3; }
      else             { p = s4; off = i - C4; }
      float4 f = p[off];
      local += negterm(f.x);
      local += negterm(f.y);
      local += negterm(f.z);
      local += negterm(f.w);
    }
    sh[t] = local;
    __syncthreads();
    #pragma unroll
    for (int off = 128; off > 0; off >>= 1) {
      if (t < off) sh[t] += sh[t + off];
      __syncthreads();
    }
    if (t == 0) part[sb] = sh[0];
  }
}

// ---------- resolveK: dedup claims, box/ctr losses, cls corrections, finalize ----------
__global__ __launch_bounds__(1024) void resolveK(
    const int* __restrict__ win, const float4* __restrict__ gtb, const int* __restrict__ glab,
    const float* __restrict__ c0, const float* __restrict__ c1, const float* __restrict__ c2,
    const float* __restrict__ c3, const float* __restrict__ c4,
    const float* __restrict__ bb0, const float* __restrict__ bb1, const float* __restrict__ bb2,
    const float* __restrict__ bb3, const float* __restrict__ bb4,
    const float* __restrict__ ct0, const float* __restrict__ ct1, const float* __restrict__ ct2,
    const float* __restrict__ ct3, const float* __restrict__ ct4,
    const float* __restrict__ part, float* __restrict__ out) {
  int t = threadIdx.x;
  __shared__ unsigned int keys[NPB * 4];
  // key = ((b*32768 + n) << 6) | pri,  pri = tier*32 + g  (tier2 beats tier1, then larger g)
  for (int k = t; k < NPB * 4; k += 1024) {
    int blk = k >> 2, s = k & 3;
    int b = blk >> 5, g = blk & 31;
    int n = win[k];
    unsigned int pri = ((s == 3) ? 32u : 0u) + (unsigned int)g;
    keys[k] = (((unsigned int)(b * 32768 + n)) << 6) | pri;
  }
  __syncthreads();

  double a_cls = 0.0, a_pos = 0.0, a_ctr = 0.0, a_diou = 0.0, a_cbce = 0.0;

  // stream partials
  for (int i = t; i < NSTREAM; i += 1024) a_cls += (double)part[i];

  const float* clsA[5] = {c0, c1, c2, c3, c4};
  const float* bbA[5]  = {bb0, bb1, bb2, bb3, bb4};
  const float* ctA[5]  = {ct0, ct1, ct2, ct3, ct4};

  for (int k = t; k < NPB * 4; k += 1024) {
    unsigned int me = keys[k];
    unsigned int bn = me >> 6;
    int b = (int)(bn >> 15);
    int base = b * 128;                 // this image's 128 candidate slots
    bool alive = true;
    #pragma unroll 4
    for (int j = 0; j < 128; ++j) {
      unsigned int o = keys[base + j];
      if ((o >> 6) == bn && o > me) { alive = false; }
    }
    if (!alive) continue;

    int n = (int)(bn & 32767u);
    int g = (int)(me & 31u);
    int lab = glab[b * NGT + g];
    float4 gb = gtb[b * NGT + g];
    Geo G = geom(n);

    const float* bb = bbA[G.lvl];
    const float* ct = ctA[G.lvl];
    const float* cp = clsA[G.lvl];

    const float* bp = bb + b * 4 * G.HW + G.j;
    float f0 = bp[0];
    float f1 = bp[G.HW];
    float f2 = bp[2 * G.HW];
    float f3 = bp[3 * G.HW];
    float fo = ct[b * G.HW + G.j];
    float xc = cp[((size_t)(b * 81 + lab)) * G.HW + G.j];

    // cls correction: posterm - negterm at the target logit
    {
      float ax = fabsf(xc);
      float e  = fexp2(ax * -L2E);
      float r  = frcp(1.0f + e);
      float p  = (xc >= 0.0f) ? r : e * r;
      float sp = fmaxf(xc, 0.0f) + flog2(1.0f + e) * LN2;
      float neg = 0.75f * (p * p) * sp;
      float omp = 1.0f - p;
      float pos = 0.25f * (omp * omp) * (sp - xc);
      a_cls += (double)(pos - neg);
    }

    float tx = G.px - gb.x, ty = G.py - gb.y, tz = gb.z - G.px, tw = gb.w - G.py;

    float lr_min = fminf(tx, tz), lr_max = fmaxf(tx, tz);
    float tb_min = fminf(ty, tw), tb_max = fmaxf(ty, tw);
    float prod = (lr_min / lr_max) * (tb_min / tb_max);
    float ctrt = sqrtf(fmaxf(prod, 0.0f));

    float pb0 = G.px - f0, pb1 = G.py - f1, pb2 = G.px + f2, pb3 = G.py + f3;
    float tb0 = G.px - tx, tb1 = G.py - ty, tb2 = G.px + tz, tb3 = G.py + tw;

    float ltx = fmaxf(pb0, tb0), lty = fmaxf(pb1, tb1);
    float rbx = fminf(pb2, tb2), rby = fminf(pb3, tb3);
    float whx = fmaxf(rbx - ltx, 0.0f), why = fmaxf(rby - lty, 0.0f);
    float ovl = whx * why;
    float ap = (pb2 - pb0) * (pb3 - pb1);
    float ag = (tb2 - tb0) * (tb3 - tb1);
    float ious = ovl / (ap + ag - ovl + EPSF);
    float eltx = fminf(pb0, tb0), elty = fminf(pb1, tb1);
    float erbx = fmaxf(pb2, tb2), erby = fmaxf(pb3, tb3);
    float ewx = fmaxf(erbx - eltx, 0.0f), ewy = fmaxf(erby - elty, 0.0f);
    float c2v = ewx * ewx + ewy * ewy + EPSF;
    float sx = pb0 + pb2 - tb0 - tb2;
    float sy = pb1 + pb3 - tb1 - tb3;
    float rho2 = (sx * sx + sy * sy) * 0.25f;
    float dl = 1.0f - (ious - rho2 / c2v);

    a_pos  += 1.0;
    a_ctr  += (double)ctrt;
    a_diou += (double)(dl * ctrt);
    a_cbce += (double)(fmaxf(fo, 0.0f) - fo * ctrt + log1pf(expf(-fabsf(fo))));
  }

  __shared__ double r0[1024], r1[1024], r2[1024], r3[1024], r4[1024];
  r0[t] = a_cls; r1[t] = a_pos; r2[t] = a_ctr; r3[t] = a_diou; r4[t] = a_cbce;
  __syncthreads();
  #pragma unroll
  for (int off = 512; off > 0; off >>= 1) {
    if (t < off) {
      r0[t] += r0[t + off]; r1[t] += r1[t + off]; r2[t] += r2[t + off];
      r3[t] += r3[t + off]; r4[t] += r4[t + off];
    }
    __syncthreads();
  }
  if (t == 0) {
    double np_ = r1[0] > 1.0 ? r1[0] : 1.0;
    double dn  = r2[0] > 1e-6 ? r2[0] : 1e-6;
    out[0] = (float)(r0[0] / np_);
    out[1] = (float)(r3[0] / dn);
    out[2] = (float)(r4[0] / np_);
  }
}

extern "C" void kernel_launch(void* const* d_in, const int* in_sizes, int n_in,
                              void* d_out, int out_size, void* d_ws, size_t ws_size,
                              hipStream_t stream) {
  (void)in_sizes; (void)n_in; (void)out_size; (void)ws_size;
  const float* cls[5] = {(const float*)d_in[0],  (const float*)d_in[3],  (const float*)d_in[6],
                         (const float*)d_in[9],  (const float*)d_in[12]};
  const float* bbx[5] = {(const float*)d_in[1],  (const float*)d_in[4],  (const float*)d_in[7],
                         (const float*)d_in[10], (const float*)d_in[13]};
  const float* ctr[5] = {(const float*)d_in[2],  (const float*)d_in[5],  (const float*)d_in[8],
                         (const float*)d_in[11], (const float*)d_in[14]};
  const float4* gtb = (const float4*)d_in[15];
  const int* glab = (const int*)d_in[16];

  char* ws = (char*)d_ws;
  int4*  win  = (int4*)ws;                       // 512 * 16 B = 8 KB
  float* part = (float*)(ws + NPB * 16);         // 2048 floats

  megaK<<<NPB + NSTREAM, 256, 0, stream>>>(gtb,
                                           (const float4*)cls[0], (const float4*)cls[1],
                                           (const float4*)cls[2], (const float4*)cls[3],
                                           (const float4*)cls[4],
                                           win, part);
  resolveK<<<1, 1024, 0, stream>>>((const int*)win, gtb, glab,
                                   cls[0], cls[1], cls[2], cls[3], cls[4],
                                   bbx[0], bbx[1], bbx[2], bbx[3], bbx[4],
                                   ctr[0], ctr[1], ctr[2], ctr[3], ctr[4],
                                   part, (float*)d_out);
}